// Round 5
// baseline (23285.818 us; speedup 1.0000x reference)
//
#include <hip/hip_runtime.h>

typedef _Float16 f16;
typedef _Float16 f16x8 __attribute__((ext_vector_type(8)));
typedef float f32x4 __attribute__((ext_vector_type(4)));
typedef unsigned long long u64;
typedef unsigned short u16;

#define NB 32
#define NT 2048
#define ND 512
#define NH 512
#define NWG 32
#define SENTH ((u16)0xFFFFu)
#define SLOT 8192            // halfwords per slot: 16 batches x 512 cols
#define SLOT64 2048          // u64 per slot

__device__ __forceinline__ float sigf(float x)  { return 1.0f / (1.0f + __expf(-x)); }
__device__ __forceinline__ float tanhf_(float x){ return 2.0f / (1.0f + __expf(-2.0f * x)) - 1.0f; }

// any halfword of x == 0xFFFF ?  (fp16 h = og*tanh(c), |h|<1 -> never 0xFFFF)
__device__ __forceinline__ bool has_sent(u64 x) {
  u64 a = x & (x >> 8); a &= (a >> 4); a &= (a >> 2); a &= (a >> 1);
  return (a & 0x0001000100010001ull) != 0ull;
}

// ---- init: per chain, slot0 = h_prev (f16, [m][col]); slots 1..3 = sentinel ----
__global__ void lstm_init(const float* __restrict__ hprev, u16* __restrict__ hg) {
  const int g = blockIdx.x * 256 + threadIdx.x;     // 0..65535
  const int ch = g >> 15, r = g & 32767, slot = r >> 13, idx = r & 8191;
  u16 v;
  if (slot == 0) {
    const int m = idx >> 9, col = idx & 511;
    union { f16 h; u16 u; } cv; cv.h = (f16)hprev[(size_t)(ch * 16 + m) * NH + col];
    v = cv.u;
  } else v = SENTH;
  hg[(size_t)(ch * 4 + slot) * SLOT + idx] = v;
}

// ---- xcvt: X f32 -> f16 MFMA B-fragment image per (t, chain):
// Xh[(t*2+ch)][ ((d>>5)*64 + ((d&31)>>3)*16 + b)*8 + (d&7) ] = x[b][t][d] ----
__global__ void __launch_bounds__(256, 1)
lstm_xcvt(const float* __restrict__ X, f16* __restrict__ Xh) {
  const int t = blockIdx.x, ch = blockIdx.y, tid = threadIdx.x;
  const int b = tid & 15, d0 = (tid >> 4) * 32;
  const float* src = X + ((size_t)(ch * 16 + b) * NT + t) * ND + d0;
  f16* dst = Xh + ((size_t)t * 2 + ch) * SLOT;
  f32x4 v[8];
#pragma unroll
  for (int i = 0; i < 8; ++i) v[i] = *(const f32x4*)(src + 4 * i);
#pragma unroll
  for (int q = 0; q < 4; ++q) {
    f16x8 o;
#pragma unroll
    for (int e = 0; e < 8; ++e) o[e] = (f16)v[q * 2 + (e >> 2)][e & 3];
    *(f16x8*)&dst[((d0 >> 5) * 64 + q * 16 + b) * 8] = o;
  }
}

// ---- persistent recurrent kernel: 32 WGs x 256 threads, 2 interleaved chains ----
__global__ void __launch_bounds__(256, 1)
lstm_rec(const float* __restrict__ Whh,   // [4H][H] f32
         const float* __restrict__ Wih,   // [4H][D] f32
         const float* __restrict__ bias,  // [4H]
         const f16*   __restrict__ Xh,    // [T][2][SLOT] fragment image
         float* __restrict__ out,         // [32][512]
         u16*   __restrict__ hg) {        // [2 ch][4 slots][SLOT]
  __shared__ __align__(16) f16 hA[SLOT];  // [kt 16][lane 64][e 8]
  __shared__ __align__(16) f16 hB[SLOT];

  const int tid  = threadIdx.x;
  const int wgid = blockIdx.x;
  const int wv   = tid >> 6;
  const int lane = tid & 63;
  const int l15  = lane & 15;
  const int lg   = lane >> 4;              // 0..3
  const int colW = wgid * 16 + wv * 4;     // wave's 4 cols
  const int fq   = l15 & 3, fc = l15 >> 2; // A-frag row rr=l15 -> (type fq, col fc)
  const int mycol = colW + lg;             // this lane's output column

  // --- resident weight fragments (A-operand): 128 VGPRs total ---
  f16x8 wfh[16], wfx[16];
#pragma unroll
  for (int kt = 0; kt < 16; ++kt) {
    const float* s1 = Whh + ((size_t)fq * NH + colW + fc) * NH + kt * 32 + lg * 8;
    const float* s2 = Wih + ((size_t)fq * NH + colW + fc) * ND + kt * 32 + lg * 8;
    f16x8 a, b;
#pragma unroll
    for (int e = 0; e < 8; ++e) { a[e] = (f16)s1[e]; b[e] = (f16)s2[e]; }
    wfh[kt] = a; wfx[kt] = b;
  }
  float bs[4];
#pragma unroll
  for (int q = 0; q < 4; ++q) bs[q] = bias[q * NH + mycol];

  const int gw0  = l15 * 128 + wv * 32 + lg * 8;  // first of 8 gathered u64 words
  const int pidx = l15 * 512 + mycol;             // publish halfword index

  u64* hg64 = (u64*)hg;     // chain A slots at s*SLOT64, chain B at (4+s)*SLOT64
  float cA = 0.f, cB = 0.f;

  // prologue: issue gathers for slot 0 of both chains
  u64 gA[8], gB[8];
#pragma unroll
  for (int i = 0; i < 8; ++i)
    gA[i] = __hip_atomic_load(hg64 + gw0 + i, __ATOMIC_RELAXED, __HIP_MEMORY_SCOPE_AGENT);
#pragma unroll
  for (int i = 0; i < 8; ++i)
    gB[i] = __hip_atomic_load(hg64 + 4 * SLOT64 + gw0 + i, __ATOMIC_RELAXED, __HIP_MEMORY_SCOPE_AGENT);

  for (int t = 0; t < NT; ++t) {
    // ================= chain A: spin + scatter =================
    {
      u64* src = hg64 + (size_t)(t & 3) * SLOT64 + gw0;
      while (true) {
        unsigned bad = 0;
#pragma unroll
        for (int i = 0; i < 8; ++i) if (has_sent(gA[i])) bad |= 1u << i;
        if (!__any(bad)) break;
#pragma unroll
        for (int i = 0; i < 8; ++i)
          if (bad & (1u << i))
            gA[i] = __hip_atomic_load(src + i, __ATOMIC_RELAXED, __HIP_MEMORY_SCOPE_AGENT);
      }
#pragma unroll
      for (int i = 0; i < 8; ++i)
        *(u64*)&hA[(((wv * 4 + lg) * 64 + (i >> 1) * 16 + l15) << 3) + 4 * (i & 1)] = gA[i];
    }
    __syncthreads();   // BAR1: h_A(t) staged
    // ================= chain A: compute ========================
    {
      const f16* xb = Xh + ((size_t)t * 2 + 0) * SLOT + lane * 8;
      f32x4 acc = {0, 0, 0, 0};
#pragma unroll
      for (int kt = 0; kt < 16; ++kt) {
        f16x8 hf = *(const f16x8*)&hA[(kt * 64 + lane) * 8];
        acc = __builtin_amdgcn_mfma_f32_16x16x32_f16(wfh[kt], hf, acc, 0, 0, 0);
      }
#pragma unroll
      for (int kt = 0; kt < 16; ++kt) {
        f16x8 xf = *(const f16x8*)(xb + kt * 512);
        acc = __builtin_amdgcn_mfma_f32_16x16x32_f16(wfx[kt], xf, acc, 0, 0, 0);
      }
      float ig = sigf(acc[0] + bs[0]);
      float fg = sigf(acc[1] + bs[1]);
      float gg = tanhf_(acc[2] + bs[2]);
      float og = sigf(acc[3] + bs[3]);
      cA = fg * cA + ig * gg;
      float hv = og * tanhf_(cA);
      union { f16 h; u16 u; } cv; cv.h = (f16)hv;
      __hip_atomic_store(hg + (size_t)((t + 1) & 3) * SLOT + pidx, cv.u,
                         __ATOMIC_RELAXED, __HIP_MEMORY_SCOPE_AGENT);
      __hip_atomic_store(hg + (size_t)((t + 3) & 3) * SLOT + pidx, SENTH,
                         __ATOMIC_RELAXED, __HIP_MEMORY_SCOPE_AGENT);
      if (t == NT - 1) out[(size_t)l15 * NH + mycol] = hv;
      if (t < NT - 1) {
        u64* nsrc = hg64 + (size_t)((t + 1) & 3) * SLOT64 + gw0;
#pragma unroll
        for (int i = 0; i < 8; ++i)
          gA[i] = __hip_atomic_load(nsrc + i, __ATOMIC_RELAXED, __HIP_MEMORY_SCOPE_AGENT);
      }
    }
    // ================= chain B: spin + scatter =================
    {
      u64* src = hg64 + (size_t)(4 + (t & 3)) * SLOT64 + gw0;
      while (true) {
        unsigned bad = 0;
#pragma unroll
        for (int i = 0; i < 8; ++i) if (has_sent(gB[i])) bad |= 1u << i;
        if (!__any(bad)) break;
#pragma unroll
        for (int i = 0; i < 8; ++i)
          if (bad & (1u << i))
            gB[i] = __hip_atomic_load(src + i, __ATOMIC_RELAXED, __HIP_MEMORY_SCOPE_AGENT);
      }
#pragma unroll
      for (int i = 0; i < 8; ++i)
        *(u64*)&hB[(((wv * 4 + lg) * 64 + (i >> 1) * 16 + l15) << 3) + 4 * (i & 1)] = gB[i];
    }
    __syncthreads();   // BAR2: h_B(t) staged
    // ================= chain B: compute ========================
    {
      const f16* xb = Xh + ((size_t)t * 2 + 1) * SLOT + lane * 8;
      f32x4 acc = {0, 0, 0, 0};
#pragma unroll
      for (int kt = 0; kt < 16; ++kt) {
        f16x8 hf = *(const f16x8*)&hB[(kt * 64 + lane) * 8];
        acc = __builtin_amdgcn_mfma_f32_16x16x32_f16(wfh[kt], hf, acc, 0, 0, 0);
      }
#pragma unroll
      for (int kt = 0; kt < 16; ++kt) {
        f16x8 xf = *(const f16x8*)(xb + kt * 512);
        acc = __builtin_amdgcn_mfma_f32_16x16x32_f16(wfx[kt], xf, acc, 0, 0, 0);
      }
      float ig = sigf(acc[0] + bs[0]);
      float fg = sigf(acc[1] + bs[1]);
      float gg = tanhf_(acc[2] + bs[2]);
      float og = sigf(acc[3] + bs[3]);
      cB = fg * cB + ig * gg;
      float hv = og * tanhf_(cB);
      union { f16 h; u16 u; } cv; cv.h = (f16)hv;
      __hip_atomic_store(hg + (size_t)(4 + ((t + 1) & 3)) * SLOT + pidx, cv.u,
                         __ATOMIC_RELAXED, __HIP_MEMORY_SCOPE_AGENT);
      __hip_atomic_store(hg + (size_t)(4 + ((t + 3) & 3)) * SLOT + pidx, SENTH,
                         __ATOMIC_RELAXED, __HIP_MEMORY_SCOPE_AGENT);
      if (t == NT - 1) out[(size_t)(16 + l15) * NH + mycol] = hv;
      if (t < NT - 1) {
        u64* nsrc = hg64 + (size_t)(4 + ((t + 1) & 3)) * SLOT64 + gw0;
#pragma unroll
        for (int i = 0; i < 8; ++i)
          gB[i] = __hip_atomic_load(nsrc + i, __ATOMIC_RELAXED, __HIP_MEMORY_SCOPE_AGENT);
      }
    }
  }
}

extern "C" void kernel_launch(void* const* d_in, const int* in_sizes, int n_in,
                              void* d_out, int out_size, void* d_ws, size_t ws_size,
                              hipStream_t stream) {
  const float* X     = (const float*)d_in[0];  // [32][2048][512]
  const float* hprev = (const float*)d_in[1];  // [32][512]
  const float* Wih   = (const float*)d_in[2];  // [2048][512]
  const float* Whh   = (const float*)d_in[3];  // [2048][512]
  const float* bias  = (const float*)d_in[4];  // [2048]
  float* out = (float*)d_out;

  u16* hg = (u16*)d_ws;                               // 2*4*SLOT*2B = 128 KB
  f16* Xh = (f16*)((char*)d_ws + (size_t)(1 << 17));  // NT*2*SLOT*2B = 64 MB

  hipLaunchKernelGGL(lstm_init, dim3(256), dim3(256), 0, stream, hprev, hg);
  hipLaunchKernelGGL(lstm_xcvt, dim3(NT, 2), dim3(256), 0, stream, X, Xh);
  hipLaunchKernelGGL(lstm_rec, dim3(NWG), dim3(256), 0, stream,
                     Whh, Wih, bias, Xh, out, hg);
}

// Round 7
// 12581.811 us; speedup vs baseline: 1.8508x; 1.8508x over previous
//
#include <hip/hip_runtime.h>

typedef _Float16 f16;
typedef _Float16 f16x8 __attribute__((ext_vector_type(8)));
typedef float f32x4 __attribute__((ext_vector_type(4)));
typedef unsigned long long u64;
typedef unsigned short u16;
typedef unsigned int u32;

#define NT 2048
#define ND 512
#define NH 512
#define NWG 16
#define SENTW 0xFFFFFFFFFFFFFFFFull
#define SENTH ((u16)0xFFFFu)

__device__ __forceinline__ float sigf(float x)  { return 1.0f / (1.0f + __expf(-x)); }
__device__ __forceinline__ float tanhf_(float x){ return 2.0f / (1.0f + __expf(-2.0f * x)) - 1.0f; }

// any halfword of x == 0xFFFF ? (h = og*tanh(c), |h|<1 -> f16 pattern 0xFFFF unreachable)
__device__ __forceinline__ bool has_sent(u64 x) {
  u64 a = x & (x >> 8); a &= (a >> 4); a &= (a >> 2); a &= (a >> 1);
  return (a & 0x0001000100010001ull) != 0ull;
}

// fragment-linear LDS index (in 8-halfword units) for (batch b, col k0), k0 % 8 == 0
// layout: [kt 16][bh 2][lane 64][e 8];  lane = ((k0&31)>>3)*16 + (b&15)
__device__ __forceinline__ int frag_idx(int b, int k0) {
  return ((k0 >> 5) * 2 + (b >> 4)) * 64 + ((k0 & 31) >> 3) * 16 + (b & 15);
}

// ---- init: hg slot0 = h_prev (f16), slots 1..3 = sentinel; all via LLC ----
__global__ void lstm_init(const float* __restrict__ hprev, u64* __restrict__ hg) {
  const int g = blockIdx.x * 256 + threadIdx.x;    // 0..16383
  const int slot = g >> 12, idx = g & 4095;
  u64 v = SENTW;
  if (slot == 0) {
    const int b = idx >> 7, c0 = (idx & 127) << 2;
    const float* s = hprev + b * NH + c0;
    union { u64 u; f16 h[4]; } pk;
    pk.h[0] = (f16)s[0]; pk.h[1] = (f16)s[1]; pk.h[2] = (f16)s[2]; pk.h[3] = (f16)s[3];
    v = pk.u;
  }
  __hip_atomic_store(hg + g, v, __ATOMIC_RELAXED, __HIP_MEMORY_SCOPE_AGENT);
}

// ---- xproj: xp[t][col][b] = u64{4 gates f16} = Wih.x_t + bias ----
// grid (128 tb, 32 cb) x 256 threads; WG covers 16 t-steps x 16 cols x 32 batches
__global__ void __launch_bounds__(256, 1)
lstm_xproj(const float* __restrict__ X, const float* __restrict__ Wih,
           const float* __restrict__ bias, u64* __restrict__ xp) {
  __shared__ __align__(16) f16 x_lds[16384];
  const int tid = threadIdx.x, lane = tid & 63;
  const int wv = tid >> 6, l15 = lane & 15, lg = lane >> 4;
  const int tb = blockIdx.x, cb = blockIdx.y;
  const int colbase = cb * 16 + wv * 4;

  // A-frags: rows rr=l15 -> (gate rr&3, colq rr>>2)
  f16x8 wf[16];
#pragma unroll
  for (int kt = 0; kt < 16; ++kt) {
    const float* src = Wih + ((size_t)(l15 & 3) * NH + colbase + (l15 >> 2)) * ND + kt * 32 + lg * 8;
    f32x4 u0 = *(const f32x4*)src, u1 = *(const f32x4*)(src + 4);
    f16x8 w;
    w[0]=(f16)u0[0]; w[1]=(f16)u0[1]; w[2]=(f16)u0[2]; w[3]=(f16)u0[3];
    w[4]=(f16)u1[0]; w[5]=(f16)u1[1]; w[6]=(f16)u1[2]; w[7]=(f16)u1[3];
    wf[kt] = w;
  }
  const int mycol = colbase + lg;
  float bs[4];
#pragma unroll
  for (int q = 0; q < 4; ++q) bs[q] = bias[q * NH + mycol];

  const int gb = tid >> 3, gc0 = (tid & 7) * 64;   // staging ownership

  for (int tt = 0; tt < 16; ++tt) {
    const int t = tb * 16 + tt;
    // stage x(t) into fragment-linear LDS (coalesced f32 loads)
    const float* xs = X + ((size_t)gb * NT + t) * ND + gc0;
#pragma unroll
    for (int i = 0; i < 8; ++i) {
      f32x4 v0 = *(const f32x4*)(xs + 8 * i);
      f32x4 v1 = *(const f32x4*)(xs + 8 * i + 4);
      f16x8 h8;
      h8[0]=(f16)v0[0]; h8[1]=(f16)v0[1]; h8[2]=(f16)v0[2]; h8[3]=(f16)v0[3];
      h8[4]=(f16)v1[0]; h8[5]=(f16)v1[1]; h8[6]=(f16)v1[2]; h8[7]=(f16)v1[3];
      *(f16x8*)&x_lds[frag_idx(gb, gc0 + 8 * i) * 8] = h8;
    }
    __syncthreads();

    f32x4 acc0 = {0,0,0,0}, acc1 = {0,0,0,0};
#pragma unroll
    for (int kt = 0; kt < 16; ++kt) {
      f16x8 b0 = *(const f16x8*)&x_lds[((kt * 2 + 0) * 64 + lane) * 8];
      f16x8 b1 = *(const f16x8*)&x_lds[((kt * 2 + 1) * 64 + lane) * 8];
      acc0 = __builtin_amdgcn_mfma_f32_16x16x32_f16(wf[kt], b0, acc0, 0, 0, 0);
      acc1 = __builtin_amdgcn_mfma_f32_16x16x32_f16(wf[kt], b1, acc1, 0, 0, 0);
    }
    // C: row=(lane>>4)*4+r -> gate r, colq lg; n=l15 -> batch bh*16+l15
#pragma unroll
    for (int bh = 0; bh < 2; ++bh) {
      const f32x4& a = bh ? acc1 : acc0;
      union { u64 u; f16 h[4]; } pk;
      pk.h[0] = (f16)(a[0] + bs[0]); pk.h[1] = (f16)(a[1] + bs[1]);
      pk.h[2] = (f16)(a[2] + bs[2]); pk.h[3] = (f16)(a[3] + bs[3]);
      __hip_atomic_store(xp + ((size_t)t * NH + mycol) * 32 + bh * 16 + l15, pk.u,
                         __ATOMIC_RELAXED, __HIP_MEMORY_SCOPE_AGENT);
    }
    __syncthreads();
  }
}

// ---- persistent recurrent kernel: 16 WGs x 256 threads, single chain ----
__global__ void __launch_bounds__(256, 1)
lstm_rec(const float* __restrict__ Whh,   // [4H][H] f32
         const u64*   __restrict__ xp,    // [T][512][32] u64 (4 gates f16)
         float* __restrict__ out,         // [32][512] f32
         u64*   __restrict__ hg) {        // [4][4096] u64 (f16 pieces)
  __shared__ __align__(16) f16 hbuf[2][16384];

  const int tid = threadIdx.x, lane = tid & 63;
  const int wv = tid >> 6, l15 = lane & 15, lg = lane >> 4;
  const int wgid = blockIdx.x;
  const int colW = wgid * 32 + wv * 8;

  // resident Whh A-frags: 2 col-quads x 16 kt = 128 VGPRs
  f16x8 wfa[2][16];
#pragma unroll
  for (int a = 0; a < 2; ++a)
#pragma unroll
    for (int kt = 0; kt < 16; ++kt) {
      const float* src = Whh + ((size_t)(l15 & 3) * NH + colW + a * 4 + (l15 >> 2)) * NH + kt * 32 + lg * 8;
      f32x4 u0 = *(const f32x4*)src, u1 = *(const f32x4*)(src + 4);
      f16x8 w;
      w[0]=(f16)u0[0]; w[1]=(f16)u0[1]; w[2]=(f16)u0[2]; w[3]=(f16)u0[3];
      w[4]=(f16)u1[0]; w[5]=(f16)u1[1]; w[6]=(f16)u1[2]; w[7]=(f16)u1[3];
      wfa[a][kt] = w;
    }

  // gather ownership: batch gb = tid&31, col chunk gc0 = (tid>>5)*64
  const int gb = tid & 31, gc0 = (tid >> 5) * 64;
  const int gword = gb * 128 + (tid >> 5) * 16;     // first of 16 u64 words

  u16* hgh = (u16*)hg;
  // my 4 outputs: (a, bh): batch bh*16+l15, col colW + a*4 + lg
  int paddr[2][2], qaddr[2][2];
#pragma unroll
  for (int a = 0; a < 2; ++a)
#pragma unroll
    for (int bh = 0; bh < 2; ++bh) {
      const int b = bh * 16 + l15, col = colW + a * 4 + lg;
      paddr[a][bh] = b * NH + col;            // hg halfword / out index
      qaddr[a][bh] = col * 32 + b;            // xp u64 index within t
    }

  float c[2][2] = {{0.f, 0.f}, {0.f, 0.f}};

  for (int t = 0; t < NT; ++t) {
    // (1) xp loads for this step (used ~1us later, latency hidden)
    const u64* xpt = xp + (size_t)t * 16384;
    u64 xv[2][2];
#pragma unroll
    for (int a = 0; a < 2; ++a)
#pragma unroll
      for (int bh = 0; bh < 2; ++bh) xv[a][bh] = xpt[qaddr[a][bh]];

    // (2) reset slot (t+2)&3 (provably past all gathers of it; drained by spin waits)
    // slot stride in u16 units = 4096 u64 * 4 = 16384 = 1<<14  (R6 bug: was <<13)
    {
      u16* rb = hgh + ((size_t)((t + 2) & 3) << 14);
#pragma unroll
      for (int a = 0; a < 2; ++a)
#pragma unroll
        for (int bh = 0; bh < 2; ++bh)
          __hip_atomic_store(rb + paddr[a][bh], SENTH, __ATOMIC_RELAXED, __HIP_MEMORY_SCOPE_AGENT);
    }

    // (3) spin-gather h(t) from slot t&3 (data IS the flag)
    u64 g[16];
    {
      const u64* src = hg + ((size_t)(t & 3) << 12) + gword;
#pragma unroll
      for (int i = 0; i < 16; ++i)
        g[i] = __hip_atomic_load(src + i, __ATOMIC_RELAXED, __HIP_MEMORY_SCOPE_AGENT);
      while (true) {
        u32 bad = 0;
#pragma unroll
        for (int i = 0; i < 16; ++i) if (has_sent(g[i])) bad |= 1u << i;
        if (!__any(bad != 0)) break;
#pragma unroll
        for (int i = 0; i < 16; ++i)
          if (bad & (1u << i))
            g[i] = __hip_atomic_load(src + i, __ATOMIC_RELAXED, __HIP_MEMORY_SCOPE_AGENT);
      }
    }
    asm volatile("s_waitcnt vmcnt(0)" ::: "memory");

    // (4) scatter to fragment-linear LDS (b128 writes)
    {
      u64* hb64 = (u64*)hbuf[t & 1];
#pragma unroll
      for (int i = 0; i < 16; i += 2) {
        const int fi = frag_idx(gb, gc0 + i * 4) * 2;
        hb64[fi] = g[i];
        hb64[fi + 1] = g[i + 1];
      }
    }
    __syncthreads();

    // (5) MFMA: acc[a][bh] over K=512 (linear conflict-free b128 reads)
    f32x4 acc[2][2] = {{{0,0,0,0},{0,0,0,0}},{{0,0,0,0},{0,0,0,0}}};
    {
      const f16* hb = hbuf[t & 1];
#pragma unroll
      for (int kt = 0; kt < 16; ++kt) {
        f16x8 b0 = *(const f16x8*)&hb[((kt * 2 + 0) * 64 + lane) * 8];
        f16x8 b1 = *(const f16x8*)&hb[((kt * 2 + 1) * 64 + lane) * 8];
        acc[0][0] = __builtin_amdgcn_mfma_f32_16x16x32_f16(wfa[0][kt], b0, acc[0][0], 0, 0, 0);
        acc[1][0] = __builtin_amdgcn_mfma_f32_16x16x32_f16(wfa[1][kt], b0, acc[1][0], 0, 0, 0);
        acc[0][1] = __builtin_amdgcn_mfma_f32_16x16x32_f16(wfa[0][kt], b1, acc[0][1], 0, 0, 0);
        acc[1][1] = __builtin_amdgcn_mfma_f32_16x16x32_f16(wfa[1][kt], b1, acc[1][1], 0, 0, 0);
      }
    }

    // (6) in-register cell; publish h(t+1) (acc[a][bh][r] = gate r)
    {
      u16* pb = hgh + ((size_t)((t + 1) & 3) << 14);   // (R6 bug: was <<13)
#pragma unroll
      for (int a = 0; a < 2; ++a)
#pragma unroll
        for (int bh = 0; bh < 2; ++bh) {
          const f16* xg = (const f16*)&xv[a][bh];
          float gi = acc[a][bh][0] + (float)xg[0];
          float gf = acc[a][bh][1] + (float)xg[1];
          float gg = acc[a][bh][2] + (float)xg[2];
          float go = acc[a][bh][3] + (float)xg[3];
          c[a][bh] = sigf(gf) * c[a][bh] + sigf(gi) * tanhf_(gg);
          float hv = sigf(go) * tanhf_(c[a][bh]);
          union { f16 h; u16 u; } cv; cv.h = (f16)hv;
          __hip_atomic_store(pb + paddr[a][bh], cv.u, __ATOMIC_RELAXED, __HIP_MEMORY_SCOPE_AGENT);
          if (t == NT - 1) out[paddr[a][bh]] = hv;
        }
    }
  }
}

extern "C" void kernel_launch(void* const* d_in, const int* in_sizes, int n_in,
                              void* d_out, int out_size, void* d_ws, size_t ws_size,
                              hipStream_t stream) {
  const float* X     = (const float*)d_in[0];  // [32][2048][512]
  const float* hprev = (const float*)d_in[1];  // [32][512]
  const float* Wih   = (const float*)d_in[2];  // [2048][512]
  const float* Whh   = (const float*)d_in[3];  // [2048][512]
  const float* bias  = (const float*)d_in[4];  // [2048]
  float* out = (float*)d_out;

  u64* hg = (u64*)d_ws;                               // 4*4096*8 = 128 KB
  u64* xp = (u64*)((char*)d_ws + (size_t)(1 << 17));  // 2048*512*32*8 = 256 MiB

  hipLaunchKernelGGL(lstm_init, dim3(64), dim3(256), 0, stream, hprev, hg);
  hipLaunchKernelGGL(lstm_xproj, dim3(128, 32), dim3(256), 0, stream, X, Wih, bias, xp);
  hipLaunchKernelGGL(lstm_rec, dim3(NWG), dim3(256), 0, stream, Whh, xp, out, hg);
}

// Round 8
// 9111.403 us; speedup vs baseline: 2.5557x; 1.3809x over previous
//
#include <hip/hip_runtime.h>

typedef _Float16 f16;
typedef _Float16 f16x8 __attribute__((ext_vector_type(8)));
typedef float f32x4 __attribute__((ext_vector_type(4)));
typedef unsigned long long u64;
typedef unsigned short u16;
typedef unsigned int u32;

#define NT 2048
#define ND 512
#define NH 512
#define NWG 16
#define SENTW 0xFFFFFFFFFFFFFFFFull
#define SENTH ((u16)0xFFFFu)

__device__ __forceinline__ float sigf(float x)  { return 1.0f / (1.0f + __expf(-x)); }
__device__ __forceinline__ float tanhf_(float x){ return 2.0f / (1.0f + __expf(-2.0f * x)) - 1.0f; }

// any halfword of x == 0xFFFF ? (h finite -> f16 pattern 0xFFFF (NaN) unreachable)
__device__ __forceinline__ bool has_sent(u64 x) {
  u64 a = x & (x >> 8); a &= (a >> 4); a &= (a >> 2); a &= (a >> 1);
  return (a & 0x0001000100010001ull) != 0ull;
}

// fragment-linear index (8-halfword units) for (batch b, col k0), k0%8==0:
// frag8(b,k0) = ((k0>>5)*2 + (b>>4))*64 + ((k0&31)>>3)*16 + (b&15)
// hg slot layout (u64 words 0..4095): word w covers frag8 = w>>1, cols +(w&1)*4..+3
__device__ __forceinline__ int frag_idx(int b, int k0) {
  return ((k0 >> 5) * 2 + (b >> 4)) * 64 + ((k0 & 31) >> 3) * 16 + (b & 15);
}

// ---- init: slot0 = h_prev in FRAGMENT-LINEAR order; slots 1..3 = sentinel ----
__global__ void lstm_init(const float* __restrict__ hprev, u64* __restrict__ hg) {
  const int g = blockIdx.x * 256 + threadIdx.x;    // 0..16383
  const int slot = g >> 12, w = g & 4095;
  u64 v = SENTW;
  if (slot == 0) {
    // decode word w -> (b, c0): frag8 = w>>1
    const int f8 = w >> 1;
    const int b  = ((f8 >> 6) & 1) * 16 + (f8 & 15);
    const int c0 = (f8 >> 7) * 32 + ((f8 >> 4) & 3) * 8 + (w & 1) * 4;
    const float* s = hprev + (size_t)b * NH + c0;
    union { u64 u; f16 h[4]; } pk;
    pk.h[0] = (f16)s[0]; pk.h[1] = (f16)s[1]; pk.h[2] = (f16)s[2]; pk.h[3] = (f16)s[3];
    v = pk.u;
  }
  __hip_atomic_store(hg + g, v, __ATOMIC_RELAXED, __HIP_MEMORY_SCOPE_AGENT);
}

// ---- xproj: xp[t][col][b] = u64{4 gates f16} = Wih.x_t + bias (unchanged, verified) ----
__global__ void __launch_bounds__(256, 1)
lstm_xproj(const float* __restrict__ X, const float* __restrict__ Wih,
           const float* __restrict__ bias, u64* __restrict__ xp) {
  __shared__ __align__(16) f16 x_lds[16384];
  const int tid = threadIdx.x, lane = tid & 63;
  const int wv = tid >> 6, l15 = lane & 15, lg = lane >> 4;
  const int tb = blockIdx.x, cb = blockIdx.y;
  const int colbase = cb * 16 + wv * 4;

  f16x8 wf[16];
#pragma unroll
  for (int kt = 0; kt < 16; ++kt) {
    const float* src = Wih + ((size_t)(l15 & 3) * NH + colbase + (l15 >> 2)) * ND + kt * 32 + lg * 8;
    f32x4 u0 = *(const f32x4*)src, u1 = *(const f32x4*)(src + 4);
    f16x8 w;
    w[0]=(f16)u0[0]; w[1]=(f16)u0[1]; w[2]=(f16)u0[2]; w[3]=(f16)u0[3];
    w[4]=(f16)u1[0]; w[5]=(f16)u1[1]; w[6]=(f16)u1[2]; w[7]=(f16)u1[3];
    wf[kt] = w;
  }
  const int mycol = colbase + lg;
  float bs[4];
#pragma unroll
  for (int q = 0; q < 4; ++q) bs[q] = bias[q * NH + mycol];

  const int gb = tid >> 3, gc0 = (tid & 7) * 64;

  for (int tt = 0; tt < 16; ++tt) {
    const int t = tb * 16 + tt;
    const float* xs = X + ((size_t)gb * NT + t) * ND + gc0;
#pragma unroll
    for (int i = 0; i < 8; ++i) {
      f32x4 v0 = *(const f32x4*)(xs + 8 * i);
      f32x4 v1 = *(const f32x4*)(xs + 8 * i + 4);
      f16x8 h8;
      h8[0]=(f16)v0[0]; h8[1]=(f16)v0[1]; h8[2]=(f16)v0[2]; h8[3]=(f16)v0[3];
      h8[4]=(f16)v1[0]; h8[5]=(f16)v1[1]; h8[6]=(f16)v1[2]; h8[7]=(f16)v1[3];
      *(f16x8*)&x_lds[frag_idx(gb, gc0 + 8 * i) * 8] = h8;
    }
    __syncthreads();

    f32x4 acc0 = {0,0,0,0}, acc1 = {0,0,0,0};
#pragma unroll
    for (int kt = 0; kt < 16; ++kt) {
      f16x8 b0 = *(const f16x8*)&x_lds[((kt * 2 + 0) * 64 + lane) * 8];
      f16x8 b1 = *(const f16x8*)&x_lds[((kt * 2 + 1) * 64 + lane) * 8];
      acc0 = __builtin_amdgcn_mfma_f32_16x16x32_f16(wf[kt], b0, acc0, 0, 0, 0);
      acc1 = __builtin_amdgcn_mfma_f32_16x16x32_f16(wf[kt], b1, acc1, 0, 0, 0);
    }
#pragma unroll
    for (int bh = 0; bh < 2; ++bh) {
      const f32x4& a = bh ? acc1 : acc0;
      union { u64 u; f16 h[4]; } pk;
      pk.h[0] = (f16)(a[0] + bs[0]); pk.h[1] = (f16)(a[1] + bs[1]);
      pk.h[2] = (f16)(a[2] + bs[2]); pk.h[3] = (f16)(a[3] + bs[3]);
      __hip_atomic_store(xp + ((size_t)t * NH + mycol) * 32 + bh * 16 + l15, pk.u,
                         __ATOMIC_RELAXED, __HIP_MEMORY_SCOPE_AGENT);
    }
    __syncthreads();
  }
}

// ---- persistent recurrent kernel: 16 WGs x 256 threads, single chain ----
__global__ void __launch_bounds__(256, 1)
lstm_rec(const float* __restrict__ Whh,   // [4H][H] f32
         const u64*   __restrict__ xp,    // [T][512][32] u64 (4 gates f16)
         float* __restrict__ out,         // [32][512] f32
         u64*   __restrict__ hg) {        // [4][4096] u64, FRAGMENT-LINEAR
  __shared__ __align__(16) f16 hbuf[2][16384];

  const int tid = threadIdx.x, lane = tid & 63;
  const int wv = tid >> 6, l15 = lane & 15, lg = lane >> 4;
  const int wgid = blockIdx.x;
  const int colW = wgid * 32 + wv * 8;

  // resident Whh A-frags: 2 col-quads x 16 kt = 128 VGPRs
  f16x8 wfa[2][16];
#pragma unroll
  for (int a = 0; a < 2; ++a)
#pragma unroll
    for (int kt = 0; kt < 16; ++kt) {
      const float* src = Whh + ((size_t)(l15 & 3) * NH + colW + a * 4 + (l15 >> 2)) * NH + kt * 32 + lg * 8;
      f32x4 u0 = *(const f32x4*)src, u1 = *(const f32x4*)(src + 4);
      f16x8 w;
      w[0]=(f16)u0[0]; w[1]=(f16)u0[1]; w[2]=(f16)u0[2]; w[3]=(f16)u0[3];
      w[4]=(f16)u1[0]; w[5]=(f16)u1[1]; w[6]=(f16)u1[2]; w[7]=(f16)u1[3];
      wfa[a][kt] = w;
    }

  u16* hgh = (u16*)hg;
  // my 4 outputs (a, bh): batch b = bh*16+l15, col = colW + a*4 + lg
  // frag-linear publish halfword: frag8 = (wgid*2+bh)*64 + wv*16 + l15, off a*4+lg
  int phw[2][2], qaddr[2][2], oaddr[2][2];
#pragma unroll
  for (int a = 0; a < 2; ++a)
#pragma unroll
    for (int bh = 0; bh < 2; ++bh) {
      const int b = bh * 16 + l15, col = colW + a * 4 + lg;
      phw[a][bh]   = ((wgid * 2 + bh) * 64 + wv * 16 + l15) * 8 + a * 4 + lg;
      qaddr[a][bh] = col * 32 + b;
      oaddr[a][bh] = b * NH + col;
    }

  float c[2][2] = {{0.f, 0.f}, {0.f, 0.f}};

  for (int t = 0; t < NT; ++t) {
    // (1) xp loads for this step (latency hidden under the spin)
    const u64* xpt = xp + (size_t)t * 16384;
    u64 xv[2][2];
#pragma unroll
    for (int a = 0; a < 2; ++a)
#pragma unroll
      for (int bh = 0; bh < 2; ++bh) xv[a][bh] = xpt[qaddr[a][bh]];

    // (2) reset slot (t+2)&3 (provably past all gathers of it; drained pre-publish)
    {
      u16* rb = hgh + ((size_t)((t + 2) & 3) << 14);
#pragma unroll
      for (int a = 0; a < 2; ++a)
#pragma unroll
        for (int bh = 0; bh < 2; ++bh)
          __hip_atomic_store(rb + phw[a][bh], SENTH, __ATOMIC_RELAXED, __HIP_MEMORY_SCOPE_AGENT);
    }

    // (3) spin-gather h(t), COALESCED: lane-consecutive words tid + 256*i
    u64 g[16];
    {
      const u64* src = hg + ((size_t)(t & 3) << 12) + tid;
#pragma unroll
      for (int i = 0; i < 16; ++i)
        g[i] = __hip_atomic_load(src + 256 * i, __ATOMIC_RELAXED, __HIP_MEMORY_SCOPE_AGENT);
      while (true) {
        u32 bad = 0;
#pragma unroll
        for (int i = 0; i < 16; ++i) if (has_sent(g[i])) bad |= 1u << i;
        if (!__any(bad != 0)) break;
#pragma unroll
        for (int i = 0; i < 16; ++i)
          if (bad & (1u << i))
            g[i] = __hip_atomic_load(src + 256 * i, __ATOMIC_RELAXED, __HIP_MEMORY_SCOPE_AGENT);
      }
    }
    asm volatile("s_waitcnt vmcnt(0)" ::: "memory");

    // (4) scatter to LDS = identity (hg already fragment-linear), b64 writes
    {
      u64* hb64 = (u64*)hbuf[t & 1];
#pragma unroll
      for (int i = 0; i < 16; ++i)
        hb64[tid + 256 * i] = g[i];
    }
    __syncthreads();

    // (5) MFMA: acc[a][bh] over K=512 (linear b128 reads)
    f32x4 acc[2][2] = {{{0,0,0,0},{0,0,0,0}},{{0,0,0,0},{0,0,0,0}}};
    {
      const f16* hb = hbuf[t & 1];
#pragma unroll
      for (int kt = 0; kt < 16; ++kt) {
        f16x8 b0 = *(const f16x8*)&hb[((kt * 2 + 0) * 64 + lane) * 8];
        f16x8 b1 = *(const f16x8*)&hb[((kt * 2 + 1) * 64 + lane) * 8];
        acc[0][0] = __builtin_amdgcn_mfma_f32_16x16x32_f16(wfa[0][kt], b0, acc[0][0], 0, 0, 0);
        acc[1][0] = __builtin_amdgcn_mfma_f32_16x16x32_f16(wfa[1][kt], b0, acc[1][0], 0, 0, 0);
        acc[0][1] = __builtin_amdgcn_mfma_f32_16x16x32_f16(wfa[0][kt], b1, acc[0][1], 0, 0, 0);
        acc[1][1] = __builtin_amdgcn_mfma_f32_16x16x32_f16(wfa[1][kt], b1, acc[1][1], 0, 0, 0);
      }
    }

    // (6) in-register cell; publish h(t+1) to frag-linear slot (t+1)&3
    {
      u16* pb = hgh + ((size_t)((t + 1) & 3) << 14);
#pragma unroll
      for (int a = 0; a < 2; ++a)
#pragma unroll
        for (int bh = 0; bh < 2; ++bh) {
          const f16* xg = (const f16*)&xv[a][bh];
          float gi = acc[a][bh][0] + (float)xg[0];
          float gf = acc[a][bh][1] + (float)xg[1];
          float gg = acc[a][bh][2] + (float)xg[2];
          float go = acc[a][bh][3] + (float)xg[3];
          c[a][bh] = sigf(gf) * c[a][bh] + sigf(gi) * tanhf_(gg);
          float hv = sigf(go) * tanhf_(c[a][bh]);
          union { f16 h; u16 u; } cv; cv.h = (f16)hv;
          __hip_atomic_store(pb + phw[a][bh], cv.u, __ATOMIC_RELAXED, __HIP_MEMORY_SCOPE_AGENT);
          if (t == NT - 1) out[oaddr[a][bh]] = hv;
        }
    }
  }
}

extern "C" void kernel_launch(void* const* d_in, const int* in_sizes, int n_in,
                              void* d_out, int out_size, void* d_ws, size_t ws_size,
                              hipStream_t stream) {
  const float* X     = (const float*)d_in[0];  // [32][2048][512]
  const float* hprev = (const float*)d_in[1];  // [32][512]
  const float* Wih   = (const float*)d_in[2];  // [2048][512]
  const float* Whh   = (const float*)d_in[3];  // [2048][512]
  const float* bias  = (const float*)d_in[4];  // [2048]
  float* out = (float*)d_out;

  u64* hg = (u64*)d_ws;                               // 4*4096*8 = 128 KB
  u64* xp = (u64*)((char*)d_ws + (size_t)(1 << 17));  // 2048*512*32*8 = 256 MiB

  hipLaunchKernelGGL(lstm_init, dim3(64), dim3(256), 0, stream, hprev, hg);
  hipLaunchKernelGGL(lstm_xproj, dim3(128, 32), dim3(256), 0, stream, X, Wih, bias, xp);
  hipLaunchKernelGGL(lstm_rec, dim3(NWG), dim3(256), 0, stream, Whh, xp, out, hg);
}

// Round 9
// 8937.130 us; speedup vs baseline: 2.6055x; 1.0195x over previous
//
#include <hip/hip_runtime.h>

typedef _Float16 f16;
typedef _Float16 f16x8 __attribute__((ext_vector_type(8)));
typedef float f32x4 __attribute__((ext_vector_type(4)));
typedef unsigned long long u64;
typedef unsigned short u16;
typedef unsigned int u32;

#define NT 2048
#define ND 512
#define NH 512
#define NWG 16
#define SENTW 0xFFFFFFFFFFFFFFFFull
#define SENTH ((u16)0xFFFFu)

__device__ __forceinline__ float sigf(float x)  { return 1.0f / (1.0f + __expf(-x)); }
__device__ __forceinline__ float tanhf_(float x){ return 2.0f / (1.0f + __expf(-2.0f * x)) - 1.0f; }

// any halfword of x == 0xFFFF ? (h finite -> f16 pattern 0xFFFF (NaN) unreachable)
__device__ __forceinline__ bool has_sent(u64 x) {
  u64 a = x & (x >> 8); a &= (a >> 4); a &= (a >> 2); a &= (a >> 1);
  return (a & 0x0001000100010001ull) != 0ull;
}

__device__ __forceinline__ int frag_idx(int b, int k0) {
  return ((k0 >> 5) * 2 + (b >> 4)) * 64 + ((k0 & 31) >> 3) * 16 + (b & 15);
}

// XCD-local (L2-coherent) exchange primitives: sc0 = bypass L1, served by this
// XCD's shared L2. All worker WGs are elected onto ONE XCD.
__device__ __forceinline__ void st_u16_sc0(u16* p, u32 v) {
  asm volatile("global_store_short %0, %1, off sc0" :: "v"(p), "v"(v) : "memory");
}

// gather 16 lane-consecutive u64 words (word j*256+tid), one vmcnt(0)
__device__ __forceinline__ void gather16_sc0(const u64* slot, u32 tid, u64* g) {
  const u32 voff = tid * 8u;
  asm volatile(
    "global_load_dwordx2 %0, %16, %17 sc0\n\t"
    "global_load_dwordx2 %1, %16, %17 offset:2048 sc0\n\t"
    "global_load_dwordx2 %2, %16, %18 sc0\n\t"
    "global_load_dwordx2 %3, %16, %18 offset:2048 sc0\n\t"
    "global_load_dwordx2 %4, %16, %19 sc0\n\t"
    "global_load_dwordx2 %5, %16, %19 offset:2048 sc0\n\t"
    "global_load_dwordx2 %6, %16, %20 sc0\n\t"
    "global_load_dwordx2 %7, %16, %20 offset:2048 sc0\n\t"
    "global_load_dwordx2 %8, %16, %21 sc0\n\t"
    "global_load_dwordx2 %9, %16, %21 offset:2048 sc0\n\t"
    "global_load_dwordx2 %10, %16, %22 sc0\n\t"
    "global_load_dwordx2 %11, %16, %22 offset:2048 sc0\n\t"
    "global_load_dwordx2 %12, %16, %23 sc0\n\t"
    "global_load_dwordx2 %13, %16, %23 offset:2048 sc0\n\t"
    "global_load_dwordx2 %14, %16, %24 sc0\n\t"
    "global_load_dwordx2 %15, %16, %24 offset:2048 sc0\n\t"
    "s_waitcnt vmcnt(0)"
    : "=&v"(g[0]), "=&v"(g[1]), "=&v"(g[2]), "=&v"(g[3]),
      "=&v"(g[4]), "=&v"(g[5]), "=&v"(g[6]), "=&v"(g[7]),
      "=&v"(g[8]), "=&v"(g[9]), "=&v"(g[10]), "=&v"(g[11]),
      "=&v"(g[12]), "=&v"(g[13]), "=&v"(g[14]), "=&v"(g[15])
    : "v"(voff),
      "s"(slot), "s"(slot + 512), "s"(slot + 1024), "s"(slot + 1536),
      "s"(slot + 2048), "s"(slot + 2560), "s"(slot + 3072), "s"(slot + 3584)
    : "memory");
}

// ---- init: hg slot0 = h_prev in FRAGMENT-LINEAR order; slots 1..3 = sentinel;
//      election control block reset ----
__global__ void lstm_init(const float* __restrict__ hprev, u64* __restrict__ hg,
                          int* __restrict__ ectrl) {
  const int g = blockIdx.x * 256 + threadIdx.x;    // 0..16383
  if (blockIdx.x == 0 && threadIdx.x < 16)
    __hip_atomic_store(ectrl + threadIdx.x, (threadIdx.x == 8) ? -1 : 0,
                       __ATOMIC_RELAXED, __HIP_MEMORY_SCOPE_AGENT);
  const int slot = g >> 12, w = g & 4095;
  u64 v = SENTW;
  if (slot == 0) {
    const int f8 = w >> 1;
    const int b  = ((f8 >> 6) & 1) * 16 + (f8 & 15);
    const int c0 = (f8 >> 7) * 32 + ((f8 >> 4) & 3) * 8 + (w & 1) * 4;
    const float* s = hprev + (size_t)b * NH + c0;
    union { u64 u; f16 h[4]; } pk;
    pk.h[0] = (f16)s[0]; pk.h[1] = (f16)s[1]; pk.h[2] = (f16)s[2]; pk.h[3] = (f16)s[3];
    v = pk.u;
  }
  __hip_atomic_store(hg + g, v, __ATOMIC_RELAXED, __HIP_MEMORY_SCOPE_AGENT);
}

// ---- xproj: xp[t][col][b] = u64{4 gates f16} = Wih.x_t + bias (R7/R8-verified) ----
__global__ void __launch_bounds__(256, 1)
lstm_xproj(const float* __restrict__ X, const float* __restrict__ Wih,
           const float* __restrict__ bias, u64* __restrict__ xp) {
  __shared__ __align__(16) f16 x_lds[16384];
  const int tid = threadIdx.x, lane = tid & 63;
  const int wv = tid >> 6, l15 = lane & 15, lg = lane >> 4;
  const int tb = blockIdx.x, cb = blockIdx.y;
  const int colbase = cb * 16 + wv * 4;

  f16x8 wf[16];
#pragma unroll
  for (int kt = 0; kt < 16; ++kt) {
    const float* src = Wih + ((size_t)(l15 & 3) * NH + colbase + (l15 >> 2)) * ND + kt * 32 + lg * 8;
    f32x4 u0 = *(const f32x4*)src, u1 = *(const f32x4*)(src + 4);
    f16x8 w;
    w[0]=(f16)u0[0]; w[1]=(f16)u0[1]; w[2]=(f16)u0[2]; w[3]=(f16)u0[3];
    w[4]=(f16)u1[0]; w[5]=(f16)u1[1]; w[6]=(f16)u1[2]; w[7]=(f16)u1[3];
    wf[kt] = w;
  }
  const int mycol = colbase + lg;
  float bs[4];
#pragma unroll
  for (int q = 0; q < 4; ++q) bs[q] = bias[q * NH + mycol];

  const int gb = tid >> 3, gc0 = (tid & 7) * 64;

  for (int tt = 0; tt < 16; ++tt) {
    const int t = tb * 16 + tt;
    const float* xs = X + ((size_t)gb * NT + t) * ND + gc0;
#pragma unroll
    for (int i = 0; i < 8; ++i) {
      f32x4 v0 = *(const f32x4*)(xs + 8 * i);
      f32x4 v1 = *(const f32x4*)(xs + 8 * i + 4);
      f16x8 h8;
      h8[0]=(f16)v0[0]; h8[1]=(f16)v0[1]; h8[2]=(f16)v0[2]; h8[3]=(f16)v0[3];
      h8[4]=(f16)v1[0]; h8[5]=(f16)v1[1]; h8[6]=(f16)v1[2]; h8[7]=(f16)v1[3];
      *(f16x8*)&x_lds[frag_idx(gb, gc0 + 8 * i) * 8] = h8;
    }
    __syncthreads();

    f32x4 acc0 = {0,0,0,0}, acc1 = {0,0,0,0};
#pragma unroll
    for (int kt = 0; kt < 16; ++kt) {
      f16x8 b0 = *(const f16x8*)&x_lds[((kt * 2 + 0) * 64 + lane) * 8];
      f16x8 b1 = *(const f16x8*)&x_lds[((kt * 2 + 1) * 64 + lane) * 8];
      acc0 = __builtin_amdgcn_mfma_f32_16x16x32_f16(wf[kt], b0, acc0, 0, 0, 0);
      acc1 = __builtin_amdgcn_mfma_f32_16x16x32_f16(wf[kt], b1, acc1, 0, 0, 0);
    }
#pragma unroll
    for (int bh = 0; bh < 2; ++bh) {
      const f32x4& a = bh ? acc1 : acc0;
      union { u64 u; f16 h[4]; } pk;
      pk.h[0] = (f16)(a[0] + bs[0]); pk.h[1] = (f16)(a[1] + bs[1]);
      pk.h[2] = (f16)(a[2] + bs[2]); pk.h[3] = (f16)(a[3] + bs[3]);
      __hip_atomic_store(xp + ((size_t)t * NH + mycol) * 32 + bh * 16 + l15, pk.u,
                         __ATOMIC_RELAXED, __HIP_MEMORY_SCOPE_AGENT);
    }
    __syncthreads();
  }
}

// ---- persistent recurrent kernel: 256 launched, 16 elected (one XCD) ----
__global__ void __launch_bounds__(256, 1)
lstm_rec(const float* __restrict__ Whh,   // [4H][H] f32
         const u64*   __restrict__ xp,    // [T][512][32] u64 (4 gates f16)
         float* __restrict__ out,         // [32][512] f32
         u64*   __restrict__ hg,          // [4][4096] u64, FRAGMENT-LINEAR
         int*   __restrict__ ectrl) {     // [0..7] per-XCD counters, [8] winner
  __shared__ __align__(16) f16 hbuf[2][16384];
  __shared__ int s_wg;

  const int tid = threadIdx.x;

  // ---- election: first XCD to check in 16 WGs wins; its first 16 = workers ----
  u32 xcc;
  asm volatile("s_getreg_b32 %0, hwreg(HW_REG_XCC_ID)" : "=s"(xcc));
  xcc &= 7;
  if (tid == 0) {
    int r = __hip_atomic_fetch_add(ectrl + xcc, 1, __ATOMIC_RELAXED, __HIP_MEMORY_SCOPE_AGENT);
    if (r == NWG - 1) {
      int exp = -1;
      __hip_atomic_compare_exchange_strong(ectrl + 8, &exp, (int)xcc,
          __ATOMIC_RELAXED, __ATOMIC_RELAXED, __HIP_MEMORY_SCOPE_AGENT);
    }
    int w;
    do { w = __hip_atomic_load(ectrl + 8, __ATOMIC_RELAXED, __HIP_MEMORY_SCOPE_AGENT); } while (w < 0);
    s_wg = (w == (int)xcc && r < NWG) ? r : -1;
  }
  __syncthreads();
  if (s_wg < 0) return;
  const int wgid = s_wg;

  const int lane = tid & 63;
  const int wv = tid >> 6, l15 = lane & 15, lg = lane >> 4;
  const int colW = wgid * 32 + wv * 8;

  // resident Whh A-frags: 2 col-quads x 16 kt = 128 VGPRs
  f16x8 wfa[2][16];
#pragma unroll
  for (int a = 0; a < 2; ++a)
#pragma unroll
    for (int kt = 0; kt < 16; ++kt) {
      const float* src = Whh + ((size_t)(l15 & 3) * NH + colW + a * 4 + (l15 >> 2)) * NH + kt * 32 + lg * 8;
      f32x4 u0 = *(const f32x4*)src, u1 = *(const f32x4*)(src + 4);
      f16x8 w;
      w[0]=(f16)u0[0]; w[1]=(f16)u0[1]; w[2]=(f16)u0[2]; w[3]=(f16)u0[3];
      w[4]=(f16)u1[0]; w[5]=(f16)u1[1]; w[6]=(f16)u1[2]; w[7]=(f16)u1[3];
      wfa[a][kt] = w;
    }

  u16* hgh = (u16*)hg;
  int phw[2][2], qaddr[2][2], oaddr[2][2];
#pragma unroll
  for (int a = 0; a < 2; ++a)
#pragma unroll
    for (int bh = 0; bh < 2; ++bh) {
      const int b = bh * 16 + l15, col = colW + a * 4 + lg;
      phw[a][bh]   = ((wgid * 2 + bh) * 64 + wv * 16 + l15) * 8 + a * 4 + lg;
      qaddr[a][bh] = col * 32 + b;
      oaddr[a][bh] = b * NH + col;
    }

  float c[2][2] = {{0.f, 0.f}, {0.f, 0.f}};
  int mode = 0;   // 0 = sc0 XCD-local fast path; 1 = agent/LLC fallback (sticky)

  for (int t = 0; t < NT; ++t) {
    // (1) xp loads (plain cached; consumed after MFMA — slack hides latency)
    const u64* xpt = xp + (size_t)t * 16384;
    u64 xv[2][2];
#pragma unroll
    for (int a = 0; a < 2; ++a)
#pragma unroll
      for (int bh = 0; bh < 2; ++bh) xv[a][bh] = xpt[qaddr[a][bh]];

    // (2) reset slot (t+2)&3 (drained by the gather's vmcnt(0) before publish)
    {
      u16* rb = hgh + ((size_t)((t + 2) & 3) << 14);
#pragma unroll
      for (int a = 0; a < 2; ++a)
#pragma unroll
        for (int bh = 0; bh < 2; ++bh)
          st_u16_sc0(rb + phw[a][bh], SENTH);
    }

    // (3) spin-gather h(t) from slot t&3 via XCD-local L2 (sc0)
    u64 g[16];
    const u64* slot = hg + ((size_t)(t & 3) << 12);
    if (mode == 0) {
      int rounds = 0;
      for (;;) {
        gather16_sc0(slot, (u32)tid, g);
        u32 bad = 0;
#pragma unroll
        for (int i = 0; i < 16; ++i) if (has_sent(g[i])) bad |= 1u << i;
        if (!__any(bad != 0)) break;
        if (++rounds == 256) { mode = 1; break; }   // containment: degrade, don't hang
      }
    }
    if (mode) {
      const u64* src = slot + tid;
#pragma unroll
      for (int i = 0; i < 16; ++i)
        g[i] = __hip_atomic_load(src + 256 * i, __ATOMIC_RELAXED, __HIP_MEMORY_SCOPE_AGENT);
      for (;;) {
        u32 bad = 0;
#pragma unroll
        for (int i = 0; i < 16; ++i) if (has_sent(g[i])) bad |= 1u << i;
        if (!__any(bad != 0)) break;
#pragma unroll
        for (int i = 0; i < 16; ++i)
          if (bad & (1u << i))
            g[i] = __hip_atomic_load(src + 256 * i, __ATOMIC_RELAXED, __HIP_MEMORY_SCOPE_AGENT);
      }
      asm volatile("s_waitcnt vmcnt(0)" ::: "memory");
    }

    // (4) scatter to LDS = identity (hg fragment-linear), b64 writes
    {
      u64* hb64 = (u64*)hbuf[t & 1];
#pragma unroll
      for (int i = 0; i < 16; ++i)
        hb64[tid + 256 * i] = g[i];
    }
    __syncthreads();

    // (5) MFMA over K=512 (linear conflict-free b128 reads)
    f32x4 acc[2][2] = {{{0,0,0,0},{0,0,0,0}},{{0,0,0,0},{0,0,0,0}}};
    {
      const f16* hb = hbuf[t & 1];
#pragma unroll
      for (int kt = 0; kt < 16; ++kt) {
        f16x8 b0 = *(const f16x8*)&hb[((kt * 2 + 0) * 64 + lane) * 8];
        f16x8 b1 = *(const f16x8*)&hb[((kt * 2 + 1) * 64 + lane) * 8];
        acc[0][0] = __builtin_amdgcn_mfma_f32_16x16x32_f16(wfa[0][kt], b0, acc[0][0], 0, 0, 0);
        acc[1][0] = __builtin_amdgcn_mfma_f32_16x16x32_f16(wfa[1][kt], b0, acc[1][0], 0, 0, 0);
        acc[0][1] = __builtin_amdgcn_mfma_f32_16x16x32_f16(wfa[0][kt], b1, acc[0][1], 0, 0, 0);
        acc[1][1] = __builtin_amdgcn_mfma_f32_16x16x32_f16(wfa[1][kt], b1, acc[1][1], 0, 0, 0);
      }
    }

    // (6) in-register cell; publish h(t+1) via sc0 stores (XCD-local visibility)
    {
      u16* pb = hgh + ((size_t)((t + 1) & 3) << 14);
#pragma unroll
      for (int a = 0; a < 2; ++a)
#pragma unroll
        for (int bh = 0; bh < 2; ++bh) {
          const f16* xg = (const f16*)&xv[a][bh];
          float gi = acc[a][bh][0] + (float)xg[0];
          float gf = acc[a][bh][1] + (float)xg[1];
          float gg = acc[a][bh][2] + (float)xg[2];
          float go = acc[a][bh][3] + (float)xg[3];
          c[a][bh] = sigf(gf) * c[a][bh] + sigf(gi) * tanhf_(gg);
          float hv = sigf(go) * tanhf_(c[a][bh]);
          union { f16 h; u16 u; } cv; cv.h = (f16)hv;
          st_u16_sc0(pb + phw[a][bh], cv.u);
          if (t == NT - 1) out[oaddr[a][bh]] = hv;
        }
    }
  }
}

extern "C" void kernel_launch(void* const* d_in, const int* in_sizes, int n_in,
                              void* d_out, int out_size, void* d_ws, size_t ws_size,
                              hipStream_t stream) {
  const float* X     = (const float*)d_in[0];  // [32][2048][512]
  const float* hprev = (const float*)d_in[1];  // [32][512]
  const float* Wih   = (const float*)d_in[2];  // [2048][512]
  const float* Whh   = (const float*)d_in[3];  // [2048][512]
  const float* bias  = (const float*)d_in[4];  // [2048]
  float* out = (float*)d_out;

  u64* hg    = (u64*)d_ws;                                     // 128 KiB
  int* ectrl = (int*)((char*)d_ws + (size_t)(1 << 17));        // 64 B used
  u64* xp    = (u64*)((char*)d_ws + (size_t)(1 << 17) + 4096); // 256 MiB

  hipLaunchKernelGGL(lstm_init, dim3(64), dim3(256), 0, stream, hprev, hg, ectrl);
  hipLaunchKernelGGL(lstm_xproj, dim3(128, 32), dim3(256), 0, stream, X, Wih, bias, xp);
  hipLaunchKernelGGL(lstm_rec, dim3(256), dim3(256), 0, stream, Whh, xp, out, hg, ectrl);
}

// Round 12
// 8543.233 us; speedup vs baseline: 2.7256x; 1.0461x over previous
//
#include <hip/hip_runtime.h>

typedef _Float16 f16;
typedef _Float16 f16x8 __attribute__((ext_vector_type(8)));
typedef float f32x4 __attribute__((ext_vector_type(4)));
typedef unsigned long long u64;
typedef unsigned short u16;
typedef unsigned int u32;

#define NT 2048
#define ND 512
#define NH 512
#define NWG 16
#define SENTW 0xFFFFFFFFFFFFFFFFull
#define SENTH ((u16)0xFFFFu)

__device__ __forceinline__ float sigf(float x)  { return 1.0f / (1.0f + __expf(-x)); }
__device__ __forceinline__ float tanhf_(float x){ return 2.0f / (1.0f + __expf(-2.0f * x)) - 1.0f; }

// any halfword of x == 0xFFFF ? (h finite -> f16 pattern 0xFFFF (NaN) unreachable)
__device__ __forceinline__ bool has_sent(u64 x) {
  u64 a = x & (x >> 8); a &= (a >> 4); a &= (a >> 2); a &= (a >> 1);
  return (a & 0x0001000100010001ull) != 0ull;
}

__device__ __forceinline__ int frag_idx(int b, int k0) {
  return ((k0 >> 5) * 2 + (b >> 4)) * 64 + ((k0 & 31) >> 3) * 16 + (b & 15);
}

// XCD-local (L2-coherent) primitives: sc0 bypasses L1, served by the XCD's L2.
__device__ __forceinline__ void st_u16_sc0(u16* p, u32 v) {
  asm volatile("global_store_short %0, %1, off sc0" :: "v"(p), "v"(v) : "memory");
}

// gather 16 lane-consecutive u64 words (word j*256+tid), one vmcnt(0).
// PROVEN-LIVE spin primitive (R9): full-slot sweep each round.
__device__ __forceinline__ void gather16_sc0(const u64* slot, u32 tid, u64* g) {
  const u32 voff = tid * 8u;
  asm volatile(
    "global_load_dwordx2 %0, %16, %17 sc0\n\t"
    "global_load_dwordx2 %1, %16, %17 offset:2048 sc0\n\t"
    "global_load_dwordx2 %2, %16, %18 sc0\n\t"
    "global_load_dwordx2 %3, %16, %18 offset:2048 sc0\n\t"
    "global_load_dwordx2 %4, %16, %19 sc0\n\t"
    "global_load_dwordx2 %5, %16, %19 offset:2048 sc0\n\t"
    "global_load_dwordx2 %6, %16, %20 sc0\n\t"
    "global_load_dwordx2 %7, %16, %20 offset:2048 sc0\n\t"
    "global_load_dwordx2 %8, %16, %21 sc0\n\t"
    "global_load_dwordx2 %9, %16, %21 offset:2048 sc0\n\t"
    "global_load_dwordx2 %10, %16, %22 sc0\n\t"
    "global_load_dwordx2 %11, %16, %22 offset:2048 sc0\n\t"
    "global_load_dwordx2 %12, %16, %23 sc0\n\t"
    "global_load_dwordx2 %13, %16, %23 offset:2048 sc0\n\t"
    "global_load_dwordx2 %14, %16, %24 sc0\n\t"
    "global_load_dwordx2 %15, %16, %24 offset:2048 sc0\n\t"
    "s_waitcnt vmcnt(0)"
    : "=&v"(g[0]), "=&v"(g[1]), "=&v"(g[2]), "=&v"(g[3]),
      "=&v"(g[4]), "=&v"(g[5]), "=&v"(g[6]), "=&v"(g[7]),
      "=&v"(g[8]), "=&v"(g[9]), "=&v"(g[10]), "=&v"(g[11]),
      "=&v"(g[12]), "=&v"(g[13]), "=&v"(g[14]), "=&v"(g[15])
    : "v"(voff),
      "s"(slot), "s"(slot + 512), "s"(slot + 1024), "s"(slot + 1536),
      "s"(slot + 2048), "s"(slot + 2560), "s"(slot + 3072), "s"(slot + 3584)
    : "memory");
}

// ---- init: hg slot0 = h_prev in FRAGMENT-LINEAR order; slots 1..3 = sentinel;
//      election control block reset (R9-verified, verbatim) ----
__global__ void lstm_init(const float* __restrict__ hprev, u64* __restrict__ hg,
                          int* __restrict__ ectrl) {
  const int g = blockIdx.x * 256 + threadIdx.x;    // 0..16383
  if (blockIdx.x == 0 && threadIdx.x < 16)
    __hip_atomic_store(ectrl + threadIdx.x, (threadIdx.x == 8) ? -1 : 0,
                       __ATOMIC_RELAXED, __HIP_MEMORY_SCOPE_AGENT);
  const int slot = g >> 12, w = g & 4095;
  u64 v = SENTW;
  if (slot == 0) {
    const int f8 = w >> 1;
    const int b  = ((f8 >> 6) & 1) * 16 + (f8 & 15);
    const int c0 = (f8 >> 7) * 32 + ((f8 >> 4) & 3) * 8 + (w & 1) * 4;
    const float* s = hprev + (size_t)b * NH + c0;
    union { u64 u; f16 h[4]; } pk;
    pk.h[0] = (f16)s[0]; pk.h[1] = (f16)s[1]; pk.h[2] = (f16)s[2]; pk.h[3] = (f16)s[3];
    v = pk.u;
  }
  __hip_atomic_store(hg + g, v, __ATOMIC_RELAXED, __HIP_MEMORY_SCOPE_AGENT);
}

// ---- xproj: xp[t][col][b] = u64{4 gates f16} = Wih.x_t + bias (R7-R9 verified) ----
__global__ void __launch_bounds__(256, 1)
lstm_xproj(const float* __restrict__ X, const float* __restrict__ Wih,
           const float* __restrict__ bias, u64* __restrict__ xp) {
  __shared__ __align__(16) f16 x_lds[16384];
  const int tid = threadIdx.x, lane = tid & 63;
  const int wv = tid >> 6, l15 = lane & 15, lg = lane >> 4;
  const int tb = blockIdx.x, cb = blockIdx.y;
  const int colbase = cb * 16 + wv * 4;

  f16x8 wf[16];
#pragma unroll
  for (int kt = 0; kt < 16; ++kt) {
    const float* src = Wih + ((size_t)(l15 & 3) * NH + colbase + (l15 >> 2)) * ND + kt * 32 + lg * 8;
    f32x4 u0 = *(const f32x4*)src, u1 = *(const f32x4*)(src + 4);
    f16x8 w;
    w[0]=(f16)u0[0]; w[1]=(f16)u0[1]; w[2]=(f16)u0[2]; w[3]=(f16)u0[3];
    w[4]=(f16)u1[0]; w[5]=(f16)u1[1]; w[6]=(f16)u1[2]; w[7]=(f16)u1[3];
    wf[kt] = w;
  }
  const int mycol = colbase + lg;
  float bs[4];
#pragma unroll
  for (int q = 0; q < 4; ++q) bs[q] = bias[q * NH + mycol];

  const int gb = tid >> 3, gc0 = (tid & 7) * 64;

  for (int tt = 0; tt < 16; ++tt) {
    const int t = tb * 16 + tt;
    const float* xs = X + ((size_t)gb * NT + t) * ND + gc0;
#pragma unroll
    for (int i = 0; i < 8; ++i) {
      f32x4 v0 = *(const f32x4*)(xs + 8 * i);
      f32x4 v1 = *(const f32x4*)(xs + 8 * i + 4);
      f16x8 h8;
      h8[0]=(f16)v0[0]; h8[1]=(f16)v0[1]; h8[2]=(f16)v0[2]; h8[3]=(f16)v0[3];
      h8[4]=(f16)v1[0]; h8[5]=(f16)v1[1]; h8[6]=(f16)v1[2]; h8[7]=(f16)v1[3];
      *(f16x8*)&x_lds[frag_idx(gb, gc0 + 8 * i) * 8] = h8;
    }
    __syncthreads();

    f32x4 acc0 = {0,0,0,0}, acc1 = {0,0,0,0};
#pragma unroll
    for (int kt = 0; kt < 16; ++kt) {
      f16x8 b0 = *(const f16x8*)&x_lds[((kt * 2 + 0) * 64 + lane) * 8];
      f16x8 b1 = *(const f16x8*)&x_lds[((kt * 2 + 1) * 64 + lane) * 8];
      acc0 = __builtin_amdgcn_mfma_f32_16x16x32_f16(wf[kt], b0, acc0, 0, 0, 0);
      acc1 = __builtin_amdgcn_mfma_f32_16x16x32_f16(wf[kt], b1, acc1, 0, 0, 0);
    }
#pragma unroll
    for (int bh = 0; bh < 2; ++bh) {
      const f32x4& a = bh ? acc1 : acc0;
      union { u64 u; f16 h[4]; } pk;
      pk.h[0] = (f16)(a[0] + bs[0]); pk.h[1] = (f16)(a[1] + bs[1]);
      pk.h[2] = (f16)(a[2] + bs[2]); pk.h[3] = (f16)(a[3] + bs[3]);
      __hip_atomic_store(xp + ((size_t)t * NH + mycol) * 32 + bh * 16 + l15, pk.u,
                         __ATOMIC_RELAXED, __HIP_MEMORY_SCOPE_AGENT);
    }
    __syncthreads();
  }
}

// ---- persistent recurrent kernel: 256 launched, 16 elected (one XCD) ----
__global__ void __launch_bounds__(256, 1)
lstm_rec(const float* __restrict__ Whh,   // [4H][H] f32
         const u64*   __restrict__ xp,    // [T][512][32] u64 (4 gates f16)
         float* __restrict__ out,         // [32][512] f32
         u64*   __restrict__ hg,          // [4][4096] u64, FRAGMENT-LINEAR
         int*   __restrict__ ectrl) {     // [0..7] per-XCD counters, [8] winner
  __shared__ __align__(16) f16 hbuf[2][16384];
  __shared__ int s_wg;

  const int tid = threadIdx.x;

  // ---- election: first XCD to check in 16 WGs wins (R9-verified) ----
  u32 xcc;
  asm volatile("s_getreg_b32 %0, hwreg(HW_REG_XCC_ID)" : "=s"(xcc));
  xcc &= 7;
  if (tid == 0) {
    int r = __hip_atomic_fetch_add(ectrl + xcc, 1, __ATOMIC_RELAXED, __HIP_MEMORY_SCOPE_AGENT);
    if (r == NWG - 1) {
      int exp = -1;
      __hip_atomic_compare_exchange_strong(ectrl + 8, &exp, (int)xcc,
          __ATOMIC_RELAXED, __ATOMIC_RELAXED, __HIP_MEMORY_SCOPE_AGENT);
    }
    int w;
    do { w = __hip_atomic_load(ectrl + 8, __ATOMIC_RELAXED, __HIP_MEMORY_SCOPE_AGENT); } while (w < 0);
    s_wg = (w == (int)xcc && r < NWG) ? r : -1;
  }
  __syncthreads();
  if (s_wg < 0) return;
  const int wgid = s_wg;

  const int lane = tid & 63;
  const int wv = tid >> 6, l15 = lane & 15, lg = lane >> 4;
  const int colW = wgid * 32 + wv * 8;

  // resident Whh A-frags: 2 col-quads x 16 kt = 128 VGPRs
  f16x8 wfa[2][16];
#pragma unroll
  for (int a = 0; a < 2; ++a)
#pragma unroll
    for (int kt = 0; kt < 16; ++kt) {
      const float* src = Whh + ((size_t)(l15 & 3) * NH + colW + a * 4 + (l15 >> 2)) * NH + kt * 32 + lg * 8;
      f32x4 u0 = *(const f32x4*)src, u1 = *(const f32x4*)(src + 4);
      f16x8 w;
      w[0]=(f16)u0[0]; w[1]=(f16)u0[1]; w[2]=(f16)u0[2]; w[3]=(f16)u0[3];
      w[4]=(f16)u1[0]; w[5]=(f16)u1[1]; w[6]=(f16)u1[2]; w[7]=(f16)u1[3];
      wfa[a][kt] = w;
    }

  u16* hgh = (u16*)hg;
  int phw[2][2], qaddr[2][2], oaddr[2][2];
#pragma unroll
  for (int a = 0; a < 2; ++a)
#pragma unroll
    for (int bh = 0; bh < 2; ++bh) {
      const int b = bh * 16 + l15, col = colW + a * 4 + lg;
      phw[a][bh]   = ((wgid * 2 + bh) * 64 + wv * 16 + l15) * 8 + a * 4 + lg;
      qaddr[a][bh] = col * 32 + b;
      oaddr[a][bh] = b * NH + col;
    }

  float c[2][2] = {{0.f, 0.f}, {0.f, 0.f}};
  int mode = 0;   // 0 = sc0 XCD-local fast path; 1 = agent/LLC fallback (sticky)

  // prologue: xv = xp(0) (drained by the first gather's vmcnt(0))
  u64 xv[2][2];
#pragma unroll
  for (int a = 0; a < 2; ++a)
#pragma unroll
    for (int bh = 0; bh < 2; ++bh) xv[a][bh] = xp[qaddr[a][bh]];

  for (int t = 0; t < NT; ++t) {
    // (1) reset slot (t+2)&3 (acked by the gather's vmcnt(0) before any publish)
    {
      u16* rb = hgh + ((size_t)((t + 2) & 3) << 14);
#pragma unroll
      for (int a = 0; a < 2; ++a)
#pragma unroll
        for (int bh = 0; bh < 2; ++bh)
          st_u16_sc0(rb + phw[a][bh], SENTH);
    }

    // (2) spin-gather h(t) from slot t&3: FULL re-gather each round (proven live)
    u64 g[16];
    const u64* slot = hg + ((size_t)(t & 3) << 12);
    if (mode == 0) {
      int rounds = 0;
      for (;;) {
        gather16_sc0(slot, (u32)tid, g);
        u32 bad = 0;
#pragma unroll
        for (int i = 0; i < 16; ++i) if (has_sent(g[i])) bad |= 1u << i;
        if (!__any(bad != 0)) break;
        if (++rounds == 256) { mode = 1; break; }   // containment: degrade, don't hang
      }
    }
    if (mode) {
      const u64* src = slot + tid;
#pragma unroll
      for (int i = 0; i < 16; ++i)
        g[i] = __hip_atomic_load(src + 256 * i, __ATOMIC_RELAXED, __HIP_MEMORY_SCOPE_AGENT);
      for (;;) {
        u32 bad = 0;
#pragma unroll
        for (int i = 0; i < 16; ++i) if (has_sent(g[i])) bad |= 1u << i;
        if (!__any(bad != 0)) break;
#pragma unroll
        for (int i = 0; i < 16; ++i)
          if (bad & (1u << i))
            g[i] = __hip_atomic_load(src + 256 * i, __ATOMIC_RELAXED, __HIP_MEMORY_SCOPE_AGENT);
      }
      asm volatile("s_waitcnt vmcnt(0)" ::: "memory");
    }

    // (3) scatter to LDS = identity (hg fragment-linear), b64 writes
    {
      u64* hb64 = (u64*)hbuf[t & 1];
#pragma unroll
      for (int i = 0; i < 16; ++i)
        hb64[tid + 256 * i] = g[i];
    }
    __syncthreads();

    // (4) prefetch xp(t+1) — consumed NEXT step; >=1 full step of slack, and the
    //     next step's gather vmcnt(0) guarantees arrival before use.
    const int tn = (t < NT - 1) ? t + 1 : NT - 1;
    const u64* xpn = xp + (size_t)tn * 16384;
    u64 xvn[2][2];
#pragma unroll
    for (int a = 0; a < 2; ++a)
#pragma unroll
      for (int bh = 0; bh < 2; ++bh) xvn[a][bh] = xpn[qaddr[a][bh]];

    // (5) MFMA over K=512 (linear conflict-free b128 reads)
    f32x4 acc[2][2] = {{{0,0,0,0},{0,0,0,0}},{{0,0,0,0},{0,0,0,0}}};
    {
      const f16* hb = hbuf[t & 1];
#pragma unroll
      for (int kt = 0; kt < 16; ++kt) {
        f16x8 b0 = *(const f16x8*)&hb[((kt * 2 + 0) * 64 + lane) * 8];
        f16x8 b1 = *(const f16x8*)&hb[((kt * 2 + 1) * 64 + lane) * 8];
        acc[0][0] = __builtin_amdgcn_mfma_f32_16x16x32_f16(wfa[0][kt], b0, acc[0][0], 0, 0, 0);
        acc[1][0] = __builtin_amdgcn_mfma_f32_16x16x32_f16(wfa[1][kt], b0, acc[1][0], 0, 0, 0);
        acc[0][1] = __builtin_amdgcn_mfma_f32_16x16x32_f16(wfa[0][kt], b1, acc[0][1], 0, 0, 0);
        acc[1][1] = __builtin_amdgcn_mfma_f32_16x16x32_f16(wfa[1][kt], b1, acc[1][1], 0, 0, 0);
      }
    }

    // (6) in-register cell with xv (prefetched LAST step); publish h(t+1) (sc0)
    {
      u16* pb = hgh + ((size_t)((t + 1) & 3) << 14);
#pragma unroll
      for (int a = 0; a < 2; ++a)
#pragma unroll
        for (int bh = 0; bh < 2; ++bh) {
          const f16* xg = (const f16*)&xv[a][bh];
          float gi = acc[a][bh][0] + (float)xg[0];
          float gf = acc[a][bh][1] + (float)xg[1];
          float gg = acc[a][bh][2] + (float)xg[2];
          float go = acc[a][bh][3] + (float)xg[3];
          c[a][bh] = sigf(gf) * c[a][bh] + sigf(gi) * tanhf_(gg);
          float hv = sigf(go) * tanhf_(c[a][bh]);
          union { f16 h; u16 u; } cv; cv.h = (f16)hv;
          st_u16_sc0(pb + phw[a][bh], cv.u);
          if (t == NT - 1) out[oaddr[a][bh]] = hv;
        }
    }

    // (7) roll xp prefetch
#pragma unroll
    for (int a = 0; a < 2; ++a)
#pragma unroll
      for (int bh = 0; bh < 2; ++bh) xv[a][bh] = xvn[a][bh];
  }
}

extern "C" void kernel_launch(void* const* d_in, const int* in_sizes, int n_in,
                              void* d_out, int out_size, void* d_ws, size_t ws_size,
                              hipStream_t stream) {
  const float* X     = (const float*)d_in[0];  // [32][2048][512]
  const float* hprev = (const float*)d_in[1];  // [32][512]
  const float* Wih   = (const float*)d_in[2];  // [2048][512]
  const float* Whh   = (const float*)d_in[3];  // [2048][512]
  const float* bias  = (const float*)d_in[4];  // [2048]
  float* out = (float*)d_out;

  u64* hg    = (u64*)d_ws;                                     // 128 KiB
  int* ectrl = (int*)((char*)d_ws + (size_t)(1 << 17));        // 64 B used
  u64* xp    = (u64*)((char*)d_ws + (size_t)(1 << 17) + 4096); // 256 MiB

  hipLaunchKernelGGL(lstm_init, dim3(64), dim3(256), 0, stream, hprev, hg, ectrl);
  hipLaunchKernelGGL(lstm_xproj, dim3(128, 32), dim3(256), 0, stream, X, Wih, bias, xp);
  hipLaunchKernelGGL(lstm_rec, dim3(256), dim3(256), 0, stream, Whh, xp, out, hg, ectrl);
}